// Round 3
// baseline (267.982 us; speedup 1.0000x reference)
//
#include <hip/hip_runtime.h>

#define FG 15
#define NPROP 512
#define NCLS 16
#define NCI 30   // B*FG
#define SCORE_T 0.05f
#define NMS_T 0.5f
#define DETS 100
#define PAIR_CAP (1 << 18)  // 262144 pairs (expected ~66K survivors)

typedef unsigned long long u64;
typedef unsigned int u32;

__device__ __forceinline__ unsigned sortable_f32(float f) {
  unsigned u = __float_as_uint(f);
  return u ^ ((u >> 31) ? 0xFFFFFFFFu : 0x80000000u);
}

__device__ __forceinline__ void mk_corners(const float* bx, float* X, float* Y) {
#pragma clang fp contract(off)
  float xc = bx[0], yc = bx[1], w = bx[2], h = bx[3], a = bx[4];
  float t = a * 0.017453292519943295f;
  float c = cosf(t), s = sinf(t);
  float hw = w * 0.5f, hh = h * 0.5f;
  float lx[4] = {-hw, hw, hw, -hw};
  float ly[4] = {-hh, -hh, hh, hh};
#pragma unroll
  for (int k = 0; k < 4; ++k) {
    X[k] = xc + lx[k] * c - ly[k] * s;
    Y[k] = yc + lx[k] * s + ly[k] * c;
  }
}

// ---------------- kernel 1: fused softmax+decode+sort+corners ----------------
__global__ void __launch_bounds__(256) k_sortdec(
    const float* __restrict__ logits, const float* __restrict__ regr,
    const float* __restrict__ prop,
    float* __restrict__ ssort,    // [NCI][NPROP] masked scores, sorted desc
    float* __restrict__ bsort,    // [NCI][NPROP][5]
    float* __restrict__ csort,    // [NCI][NPROP][8] x0..3,y0..3
    float4* __restrict__ prc,     // [NCI][NPROP] (x, y, circumradius, area)
    u64* __restrict__ mask,       // zeroed here
    int* __restrict__ pcount) {
  int ci = blockIdx.x;
  int b = ci / FG;
  int c = ci - b * FG + 1;  // class 1..15
  __shared__ float scs[NPROP];
  __shared__ float bb_s[5][NPROP];
  __shared__ u64 key[NPROP];

  for (int n = threadIdx.x; n < NPROP; n += 256) {
#pragma clang fp contract(off)
    int g = b * NPROP + n;
    const float* lg = logits + g * NCLS;
    float l[NCLS];
    float mx = -INFINITY;
#pragma unroll
    for (int q = 0; q < NCLS; ++q) { l[q] = lg[q]; mx = fmaxf(mx, l[q]); }
    float sum = 0.f, ec = 0.f;
#pragma unroll
    for (int q = 0; q < NCLS; ++q) {
      float e = expf(l[q] - mx);
      sum += e;
      if (q == c) ec = e;
    }
    float sc = ec / sum;  // bit-identical to prior k_decode path
    scs[n] = sc;
    const float* pb = prop + g * 5;
    float xc = pb[0], yc = pb[1], w = pb[2], h = pb[3], a = pb[4];
    const float* r = regr + g * 80 + c * 5;
    float dx = r[0] / 10.0f;
    float dy = r[1] / 10.0f;
    float dw = fminf(r[2] / 5.0f, 4.135166556742356f);
    float dh = fminf(r[3] / 5.0f, 4.135166556742356f);
    float da = r[4] / 10.0f;
    bb_s[0][n] = dx * w + xc;
    bb_s[1][n] = dy * h + yc;
    bb_s[2][n] = expf(dw) * w;
    bb_s[3][n] = expf(dh) * h;
    bb_s[4][n] = da * 57.29577951308232f + a;
    float m = (sc > SCORE_T) ? sc : -INFINITY;
    unsigned so = sortable_f32(m);
    key[n] = ((u64)(~so) << 32) | (unsigned)n;  // asc key = desc score, asc idx
  }
  __syncthreads();
  for (int k = 2; k <= NPROP; k <<= 1) {
    for (int j = k >> 1; j > 0; j >>= 1) {
      int t = threadIdx.x;  // 256 threads = 256 pairs
      int i1 = ((t & ~(j - 1)) << 1) | (t & (j - 1));
      int i2 = i1 | j;
      bool up = ((i1 & k) == 0);
      u64 a = key[i1], cc = key[i2];
      bool sw = up ? (a > cc) : (a < cc);
      if (sw) { key[i1] = cc; key[i2] = a; }
      __syncthreads();
    }
  }
  for (int i = threadIdx.x; i < NPROP; i += 256) {
#pragma clang fp contract(off)
    u64 kv = key[i];
    int idx = (int)(kv & 0xFFFFFFFFull);
    float v = scs[idx];
    ssort[ci * NPROP + i] = (v > SCORE_T) ? v : -INFINITY;
    float bb[5];
#pragma unroll
    for (int q = 0; q < 5; ++q) bb[q] = bb_s[q][idx];
    float* dst = bsort + (ci * NPROP + i) * 5;
#pragma unroll
    for (int q = 0; q < 5; ++q) dst[q] = bb[q];
    float X[4], Y[4];
    mk_corners(bb, X, Y);
    float* cd = csort + (ci * NPROP + i) * 8;
#pragma unroll
    for (int k = 0; k < 4; ++k) { cd[k] = X[k]; cd[4 + k] = Y[k]; }
    float rr = 0.5f * sqrtf(bb[2] * bb[2] + bb[3] * bb[3]);
    prc[ci * NPROP + i] = make_float4(bb[0], bb[1], rr, bb[2] * bb[3]);
  }
  u64* mrow = mask + (size_t)ci * NPROP * 8;
  for (int x = threadIdx.x; x < NPROP * 8; x += 256) mrow[x] = 0ull;
  if (ci == 0 && threadIdx.x == 0) *pcount = 0;
}

// ---------------- kernel 2: circumcircle reject + pair compaction ----------------
// Disjoint circumcircles => quad intersection exactly 0 => iou 0 => no bit.
__global__ void __launch_bounds__(512) k_pairs(
    const float* __restrict__ ssort, const float4* __restrict__ prc,
    u32* __restrict__ pairs, int* __restrict__ pcount) {
  int i = blockIdx.x, ci = blockIdx.y, j = threadIdx.x;
  const float* ss = ssort + ci * NPROP;
  if (!(ss[i] > SCORE_T)) return;  // block-uniform
  bool pass = false;
  if (j > i && ss[j] > SCORE_T) {
    float4 pi = prc[ci * NPROP + i];
    float4 pj = prc[ci * NPROP + j];
    float dx = pi.x - pj.x, dy = pi.y - pj.y;
    float rs = pi.z + pj.z;
    pass = (dx * dx + dy * dy) <= rs * rs;
  }
  u64 bal = __ballot(pass);
  if (bal) {
    int lane = threadIdx.x & 63;
    int base = 0;
    if (lane == 0) base = atomicAdd(pcount, (int)__popcll(bal));
    base = __shfl(base, 0);
    if (pass) {
      int pos = base + (int)__popcll(bal & ((1ull << lane) - 1ull));
      if (pos < PAIR_CAP) pairs[pos] = ((u32)ci << 18) | ((u32)i << 9) | (u32)j;
    }
  }
}

// ---------------- register Sutherland-Hodgman (fast-math; IoU slack >> rounding) --------
#define CLIP_EMIT(V, VALIDEXPR, CX, CY, NX, NY)                                \
  {                                                                            \
    bool valid = (VALIDEXPR);                                                  \
    float cx = (CX), cy = (CY), nx = (NX), ny = (NY);                          \
    float sc = ex * (cy - p1y) - ey * (cx - p1x);                              \
    float sn = ex * (ny - p1y) - ey * (nx - p1x);                              \
    bool ic = sc >= 0.f, inn = sn >= 0.f;                                      \
    float den = sc - sn;                                                       \
    float dsel = (fabsf(den) > 1e-8f) ? den : 1.f;                             \
    float tt = sc * __builtin_amdgcn_rcpf(dsel);                               \
    float qx = cx + tt * (nx - cx);                                            \
    float qy = cy + tt * (ny - cy);                                            \
    bool fC = valid && ic;                                                     \
    bool fI = valid && (ic != inn);                                            \
    _Pragma("unroll") for (int o = 0; o < 8; ++o) if (o <= 2 * (V)) {          \
      bool wr = fC && (m == o);                                                \
      ox[o] = wr ? cx : ox[o];                                                 \
      oy[o] = wr ? cy : oy[o];                                                 \
    }                                                                          \
    m += fC ? 1 : 0;                                                           \
    _Pragma("unroll") for (int o = 0; o < 8; ++o) if (o <= 2 * (V) + 1) {      \
      bool wr = fI && (m == o);                                                \
      ox[o] = wr ? qx : ox[o];                                                 \
      oy[o] = wr ? qy : oy[o];                                                 \
    }                                                                          \
    m += fI ? 1 : 0;                                                           \
  }

__device__ __forceinline__ float inter_area_fast(const float (&Ax)[4], const float (&Ay)[4],
                                                 const float (&Bx)[4], const float (&By)[4]) {
  float inx[8], iny[8];
  int n = 4;
#pragma unroll
  for (int v = 0; v < 4; ++v) {
    inx[v] = Ax[v]; iny[v] = Ay[v];
    inx[v + 4] = 0.f; iny[v + 4] = 0.f;
  }
#pragma unroll
  for (int e = 0; e < 4; ++e) {
    int e2 = (e + 1) & 3;
    float p1x = Bx[e], p1y = By[e];
    float ex = Bx[e2] - p1x, ey = By[e2] - p1y;
    float ox[8], oy[8];
    int m = 0;
#pragma unroll
    for (int o = 0; o < 8; ++o) { ox[o] = 0.f; oy[o] = 0.f; }
    if (e == 0) {  // n == 4 statically
#pragma unroll
      for (int v = 0; v < 4; ++v) {
        CLIP_EMIT(v, true, inx[v], iny[v], inx[(v + 1) & 3], iny[(v + 1) & 3]);
      }
    } else {
#pragma unroll
      for (int v = 0; v < 8; ++v) {
        bool wrap = (v + 1 >= n);
        CLIP_EMIT(v, v < n, inx[v], iny[v],
                  wrap ? inx[0] : inx[(v + 1) & 7],
                  wrap ? iny[0] : iny[(v + 1) & 7]);
      }
    }
    n = (m < 8) ? m : 8;
#pragma unroll
    for (int o = 0; o < 8; ++o) { inx[o] = ox[o]; iny[o] = oy[o]; }
  }
  float s = 0.f;
#pragma unroll
  for (int v = 0; v < 8; ++v) {
    bool valid = v < n;
    bool wrap = (v + 1 >= n);
    float axx = inx[v], ayy = iny[v];
    float bxx = wrap ? inx[0] : inx[(v + 1) & 7];
    float byy = wrap ? iny[0] : iny[(v + 1) & 7];
    float cr = axx * byy - bxx * ayy;
    s += valid ? cr : 0.f;
  }
  float area = 0.5f * fabsf(s);
  return (n >= 3) ? area : 0.f;
}

// ---------------- kernel 3: clip compacted pairs, atomicOr suppression bits ----------------
__global__ void __launch_bounds__(256) k_clip(
    const u32* __restrict__ pairs, const int* __restrict__ pcount,
    const float* __restrict__ csort, const float4* __restrict__ prc,
    u64* __restrict__ mask) {
  int cnt = *pcount;
  if (cnt > PAIR_CAP) cnt = PAIR_CAP;
  int stride = gridDim.x * blockDim.x;
  for (int p = blockIdx.x * blockDim.x + threadIdx.x; p < cnt; p += stride) {
    u32 w = pairs[p];
    int ci = w >> 18, i = (w >> 9) & 511, j = w & 511;
    const float* ca = csort + ((size_t)ci * NPROP + i) * 8;
    const float* cb = csort + ((size_t)ci * NPROP + j) * 8;
    float4 a0 = *(const float4*)ca;
    float4 a1 = *(const float4*)(ca + 4);
    float4 b0 = *(const float4*)cb;
    float4 b1 = *(const float4*)(cb + 4);
    float Ax[4] = {a0.x, a0.y, a0.z, a0.w};
    float Ay[4] = {a1.x, a1.y, a1.z, a1.w};
    float Bx[4] = {b0.x, b0.y, b0.z, b0.w};
    float By[4] = {b1.x, b1.y, b1.z, b1.w};
    float inter = inter_area_fast(Ax, Ay, Bx, By);
    float areaA = prc[ci * NPROP + i].w;
    float areaB = prc[ci * NPROP + j].w;
    float uni = (areaA + areaB) - inter;
    float iou = inter / fmaxf(uni, 1e-8f);
    if (iou > NMS_T)
      atomicOr(&mask[((size_t)ci * NPROP + i) * 8 + (j >> 6)], 1ull << (j & 63));
  }
}

// ---------------- kernel 4: greedy bitmask NMS scan + kept-key compaction ----------------
__global__ void k_nms(const float* __restrict__ ssort,
                      const u64* __restrict__ mask,
                      u64* __restrict__ kkey) {  // [NCI][128] sortable keys, desc, 0-filled
  int ci = blockIdx.x;
  int b = ci / FG, cfg = ci - b * FG;
  __shared__ u64 lmask[NPROP * 8];  // 32 KiB
  __shared__ u64 keptw[8];
  __shared__ int vcnt;
  __shared__ int wpre[8];
  const float* ss = ssort + ci * NPROP;
  if (threadIdx.x == 0) vcnt = NPROP;
  if (threadIdx.x < 8) keptw[threadIdx.x] = 0ull;
  __syncthreads();
  for (int i = threadIdx.x; i < NPROP; i += blockDim.x)
    if (!(ss[i] > SCORE_T)) atomicMin(&vcnt, i);
  __syncthreads();
  int V = vcnt;
  for (int x = threadIdx.x; x < V * 8; x += blockDim.x)
    lmask[x] = mask[(size_t)(ci * NPROP) * 8 + x];
  __syncthreads();
  if (threadIdx.x < 64) {
    int lane = threadIdx.x;
    u64 removed = 0ull, kb = 0ull;
    int kc = 0;
    for (int i = 0; i < V; ++i) {
      int w = i >> 6, bp = i & 63;
      u64 rw = __shfl(removed, w);
      if (!((rw >> bp) & 1ull)) {
        if (lane == w) kb |= (1ull << bp);
        if (lane < 8) removed |= lmask[i * 8 + lane];
        if (++kc >= DETS) break;  // first 100 kept fully determine output
      }
    }
    if (lane < 8) keptw[lane] = kb;
  }
  __syncthreads();
  if (threadIdx.x == 0) {
    int acc = 0;
#pragma unroll
    for (int w = 0; w < 8; ++w) { wpre[w] = acc; acc += (int)__popcll(keptw[w]); }
  }
  __syncthreads();
  for (int i = threadIdx.x; i < NPROP; i += blockDim.x) {
    u64 kw = keptw[i >> 6];
    if ((kw >> (i & 63)) & 1ull) {
      int rank = wpre[i >> 6] + (int)__popcll(kw & ((1ull << (i & 63)) - 1ull));
      float s = ss[i];
      u32 hi = __float_as_uint(s) ^ 0x80000000u;  // s > 0.05 > 0
      u32 flat = (u32)(cfg * NPROP + i);
      kkey[ci * 128 + rank] = ((u64)hi << 32) | (u32)(~flat);  // ties: lower flat wins max
    }
  }
  int total = wpre[7] + (int)__popcll(keptw[7]);
  for (int r = threadIdx.x; r < 128; r += blockDim.x)
    if (r >= total) kkey[ci * 128 + r] = 0ull;
}

// ---------------- kernel 5: 15-way merge of sorted kept lists -> top-100 ----------------
__global__ void k_topk(const u64* __restrict__ kkey,
                       const float* __restrict__ bsort,
                       float* __restrict__ out) {
  int b = blockIdx.x;  // 2 blocks, 128 threads
  __shared__ u64 lk[FG * 128];  // 15 KiB
  __shared__ u64 res[DETS];
  for (int x = threadIdx.x; x < FG * 128; x += 128) lk[x] = kkey[b * FG * 128 + x];
  for (int x = threadIdx.x; x < DETS; x += 128) res[x] = 0ull;
  __syncthreads();
  if (threadIdx.x < 64) {
    int lane = threadIdx.x;
    int pos = 0;
    u64 head = 0ull, nxt = 0ull;
    if (lane < FG) { head = lk[lane * 128]; nxt = lk[lane * 128 + 1]; }
    for (int r = 0; r < DETS; ++r) {
      u64 m = head;
#pragma unroll
      for (int wdt = 1; wdt < 64; wdt <<= 1) {
        u64 o = __shfl_xor(m, wdt);
        m = (o > m) ? o : m;
      }
      if (m == 0ull) break;  // uniform
      if (lane == 0) res[r] = m;
      if (head == m && lane < FG) {
        ++pos;
        head = nxt;
        nxt = (pos + 1 < 128) ? lk[lane * 128 + pos + 1] : 0ull;
      }
    }
  }
  __syncthreads();
  if (threadIdx.x < DETS) {
    u64 key = res[threadIdx.x];
    float* o = out + ((size_t)b * DETS + threadIdx.x) * 6;
    if (key == 0ull) {
#pragma unroll
      for (int q = 0; q < 6; ++q) o[q] = 0.f;
    } else {
      u32 flat = ~(u32)(key & 0xFFFFFFFFull);
      int cfg = flat >> 9, pos = flat & 511;
      const float* bx = bsort + (((size_t)b * FG + cfg) * NPROP + pos) * 5;
#pragma unroll
      for (int q = 0; q < 5; ++q) o[q] = bx[q];
      o[5] = __uint_as_float((u32)(key >> 32) ^ 0x80000000u);
    }
  }
}

extern "C" void kernel_launch(void* const* d_in, const int* in_sizes, int n_in,
                              void* d_out, int out_size, void* d_ws, size_t ws_size,
                              hipStream_t stream) {
  const float* logits = (const float*)d_in[0];
  const float* regr   = (const float*)d_in[1];
  const float* prop   = (const float*)d_in[2];
  float* out = (float*)d_out;

  float* ssort = (float*)d_ws;                        // 15360 f
  float* bsort = ssort + NCI * NPROP;                 // 76800 f
  float* csort = bsort + NCI * NPROP * 5;             // 122880 f
  float4* prc  = (float4*)(csort + NCI * NPROP * 8);  // 15360 float4 (16B-aligned offset)
  u64* kkey    = (u64*)(prc + NCI * NPROP);           // 3840 u64
  u64* mask    = kkey + NCI * 128;                    // 122880 u64
  u32* pairs   = (u32*)(mask + NCI * NPROP * 8);      // PAIR_CAP u32
  int* pcount  = (int*)(pairs + PAIR_CAP);            // 1 int   (total ~3.2 MB)

  hipLaunchKernelGGL(k_sortdec, dim3(NCI), dim3(256), 0, stream,
                     logits, regr, prop, ssort, bsort, csort, prc, mask, pcount);
  hipLaunchKernelGGL(k_pairs, dim3(NPROP, NCI), dim3(512), 0, stream,
                     ssort, prc, pairs, pcount);
  hipLaunchKernelGGL(k_clip, dim3(512), dim3(256), 0, stream,
                     pairs, pcount, csort, prc, mask);
  hipLaunchKernelGGL(k_nms, dim3(NCI), dim3(256), 0, stream, ssort, mask, kkey);
  hipLaunchKernelGGL(k_topk, dim3(2), dim3(128), 0, stream, kkey, bsort, out);
}

// Round 4
// 96.615 us; speedup vs baseline: 2.7737x; 2.7737x over previous
//
#include <hip/hip_runtime.h>

#define FG 15
#define NPROP 512
#define NCLS 16
#define NCI 30   // B*FG
#define SCORE_T 0.05f
#define NMS_T 0.5f
#define DETS 100
#define STRIPES 8
#define STAGE_CAP 4096  // per-block pair staging (expected ~300/block)

typedef unsigned long long u64;
typedef unsigned int u32;

__device__ __forceinline__ unsigned sortable_f32(float f) {
  unsigned u = __float_as_uint(f);
  return u ^ ((u >> 31) ? 0xFFFFFFFFu : 0x80000000u);
}

__device__ __forceinline__ void mk_corners(const float* bx, float* X, float* Y) {
#pragma clang fp contract(off)
  float xc = bx[0], yc = bx[1], w = bx[2], h = bx[3], a = bx[4];
  float t = a * 0.017453292519943295f;
  float c = cosf(t), s = sinf(t);
  float hw = w * 0.5f, hh = h * 0.5f;
  float lx[4] = {-hw, hw, hw, -hw};
  float ly[4] = {-hh, -hh, hh, hh};
#pragma unroll
  for (int k = 0; k < 4; ++k) {
    X[k] = xc + lx[k] * c - ly[k] * s;
    Y[k] = yc + lx[k] * s + ly[k] * c;
  }
}

// ---------------- kernel 1: fused softmax+decode+sort+corners ----------------
__global__ void __launch_bounds__(256) k_sortdec(
    const float* __restrict__ logits, const float* __restrict__ regr,
    const float* __restrict__ prop,
    float* __restrict__ ssort,    // [NCI][NPROP] masked scores, sorted desc
    float* __restrict__ bsort,    // [NCI][NPROP][5]
    float* __restrict__ csort,    // [NCI][NPROP][8] x0..3,y0..3
    float4* __restrict__ prc,     // [NCI][NPROP] (x, y, circumradius, area)
    u64* __restrict__ mask) {     // zeroed here
  int ci = blockIdx.x;
  int b = ci / FG;
  int c = ci - b * FG + 1;  // class 1..15
  __shared__ float scs[NPROP];
  __shared__ float bb_s[5][NPROP];
  __shared__ u64 key[NPROP];

  for (int n = threadIdx.x; n < NPROP; n += 256) {
#pragma clang fp contract(off)
    int g = b * NPROP + n;
    const float* lg = logits + g * NCLS;
    float l[NCLS];
    float mx = -INFINITY;
#pragma unroll
    for (int q = 0; q < NCLS; ++q) { l[q] = lg[q]; mx = fmaxf(mx, l[q]); }
    float sum = 0.f, ec = 0.f;
#pragma unroll
    for (int q = 0; q < NCLS; ++q) {
      float e = expf(l[q] - mx);
      sum += e;
      if (q == c) ec = e;
    }
    float sc = ec / sum;  // bit-identical to reference path
    scs[n] = sc;
    const float* pb = prop + g * 5;
    float xc = pb[0], yc = pb[1], w = pb[2], h = pb[3], a = pb[4];
    const float* r = regr + g * 80 + c * 5;
    float dx = r[0] / 10.0f;
    float dy = r[1] / 10.0f;
    float dw = fminf(r[2] / 5.0f, 4.135166556742356f);
    float dh = fminf(r[3] / 5.0f, 4.135166556742356f);
    float da = r[4] / 10.0f;
    bb_s[0][n] = dx * w + xc;
    bb_s[1][n] = dy * h + yc;
    bb_s[2][n] = expf(dw) * w;
    bb_s[3][n] = expf(dh) * h;
    bb_s[4][n] = da * 57.29577951308232f + a;
    float m = (sc > SCORE_T) ? sc : -INFINITY;
    unsigned so = sortable_f32(m);
    key[n] = ((u64)(~so) << 32) | (unsigned)n;  // asc key = desc score, asc idx
  }
  __syncthreads();
  for (int k = 2; k <= NPROP; k <<= 1) {
    for (int j = k >> 1; j > 0; j >>= 1) {
      int t = threadIdx.x;  // 256 threads = 256 pairs
      int i1 = ((t & ~(j - 1)) << 1) | (t & (j - 1));
      int i2 = i1 | j;
      bool up = ((i1 & k) == 0);
      u64 a = key[i1], cc = key[i2];
      bool sw = up ? (a > cc) : (a < cc);
      if (sw) { key[i1] = cc; key[i2] = a; }
      __syncthreads();
    }
  }
  for (int i = threadIdx.x; i < NPROP; i += 256) {
#pragma clang fp contract(off)
    u64 kv = key[i];
    int idx = (int)(kv & 0xFFFFFFFFull);
    float v = scs[idx];
    ssort[ci * NPROP + i] = (v > SCORE_T) ? v : -INFINITY;
    float bb[5];
#pragma unroll
    for (int q = 0; q < 5; ++q) bb[q] = bb_s[q][idx];
    float* dst = bsort + (ci * NPROP + i) * 5;
#pragma unroll
    for (int q = 0; q < 5; ++q) dst[q] = bb[q];
    float X[4], Y[4];
    mk_corners(bb, X, Y);
    float* cd = csort + (ci * NPROP + i) * 8;
#pragma unroll
    for (int k = 0; k < 4; ++k) { cd[k] = X[k]; cd[4 + k] = Y[k]; }
    float rr = 0.5f * sqrtf(bb[2] * bb[2] + bb[3] * bb[3]);
    prc[ci * NPROP + i] = make_float4(bb[0], bb[1], rr, bb[2] * bb[3]);
  }
  u64* mrow = mask + (size_t)ci * NPROP * 8;
  for (int x = threadIdx.x; x < NPROP * 8; x += 256) mrow[x] = 0ull;
}

// ---------------- register Sutherland-Hodgman (fast-math; IoU slack >> rounding) --------
#define CLIP_EMIT(V, VALIDEXPR, CX, CY, NX, NY)                                \
  {                                                                            \
    bool valid = (VALIDEXPR);                                                  \
    float cx = (CX), cy = (CY), nx = (NX), ny = (NY);                          \
    float sc = ex * (cy - p1y) - ey * (cx - p1x);                              \
    float sn = ex * (ny - p1y) - ey * (nx - p1x);                              \
    bool ic = sc >= 0.f, inn = sn >= 0.f;                                      \
    float den = sc - sn;                                                       \
    float dsel = (fabsf(den) > 1e-8f) ? den : 1.f;                             \
    float tt = sc * __builtin_amdgcn_rcpf(dsel);                               \
    float qx = cx + tt * (nx - cx);                                            \
    float qy = cy + tt * (ny - cy);                                            \
    bool fC = valid && ic;                                                     \
    bool fI = valid && (ic != inn);                                            \
    _Pragma("unroll") for (int o = 0; o < 8; ++o) if (o <= 2 * (V)) {          \
      bool wr = fC && (m == o);                                                \
      ox[o] = wr ? cx : ox[o];                                                 \
      oy[o] = wr ? cy : oy[o];                                                 \
    }                                                                          \
    m += fC ? 1 : 0;                                                           \
    _Pragma("unroll") for (int o = 0; o < 8; ++o) if (o <= 2 * (V) + 1) {      \
      bool wr = fI && (m == o);                                                \
      ox[o] = wr ? qx : ox[o];                                                 \
      oy[o] = wr ? qy : oy[o];                                                 \
    }                                                                          \
    m += fI ? 1 : 0;                                                           \
  }

__device__ __forceinline__ float inter_area_fast(const float (&Ax)[4], const float (&Ay)[4],
                                                 const float (&Bx)[4], const float (&By)[4]) {
  float inx[8], iny[8];
  int n = 4;
#pragma unroll
  for (int v = 0; v < 4; ++v) {
    inx[v] = Ax[v]; iny[v] = Ay[v];
    inx[v + 4] = 0.f; iny[v + 4] = 0.f;
  }
#pragma unroll
  for (int e = 0; e < 4; ++e) {
    int e2 = (e + 1) & 3;
    float p1x = Bx[e], p1y = By[e];
    float ex = Bx[e2] - p1x, ey = By[e2] - p1y;
    float ox[8], oy[8];
    int m = 0;
#pragma unroll
    for (int o = 0; o < 8; ++o) { ox[o] = 0.f; oy[o] = 0.f; }
    if (e == 0) {  // n == 4 statically
#pragma unroll
      for (int v = 0; v < 4; ++v) {
        CLIP_EMIT(v, true, inx[v], iny[v], inx[(v + 1) & 3], iny[(v + 1) & 3]);
      }
    } else {
#pragma unroll
      for (int v = 0; v < 8; ++v) {
        bool wrap = (v + 1 >= n);
        CLIP_EMIT(v, v < n, inx[v], iny[v],
                  wrap ? inx[0] : inx[(v + 1) & 7],
                  wrap ? iny[0] : iny[(v + 1) & 7]);
      }
    }
    n = (m < 8) ? m : 8;
#pragma unroll
    for (int o = 0; o < 8; ++o) { inx[o] = ox[o]; iny[o] = oy[o]; }
  }
  float s = 0.f;
#pragma unroll
  for (int v = 0; v < 8; ++v) {
    bool valid = v < n;
    bool wrap = (v + 1 >= n);
    float axx = inx[v], ayy = iny[v];
    float bxx = wrap ? inx[0] : inx[(v + 1) & 7];
    float byy = wrap ? iny[0] : iny[(v + 1) & 7];
    float cr = axx * byy - bxx * ayy;
    s += valid ? cr : 0.f;
  }
  float area = 0.5f * fabsf(s);
  return (n >= 3) ? area : 0.f;
}

// ---------------- kernel 2: fused circle-filter + clip ----------------
// Block (ci, s) owns rows i == s (mod 8). Pair list lives only in LDS; no
// global atomics for compaction (only atomicOr on disjoint mask rows).
__global__ void __launch_bounds__(512) k_paircl(
    const float* __restrict__ ssort, const float4* __restrict__ prc,
    const float* __restrict__ csort, u64* __restrict__ mask) {
  int ci = blockIdx.x;
  int s = blockIdx.y;
  int tid = threadIdx.x;
  int lane = tid & 63;
  __shared__ float4 prc4[NPROP];   // 8 KB
  __shared__ u32 stage[STAGE_CAP]; // 16 KB
  __shared__ int vloc, lcnt;
  const float* ss = ssort + ci * NPROP;
  if (tid == 0) { vloc = NPROP; lcnt = 0; }
  __syncthreads();
  if (!(ss[tid] > SCORE_T)) atomicMin(&vloc, tid);
  prc4[tid] = prc[ci * NPROP + tid];
  __syncthreads();
  int V = vloc;
  // phase 1: circle test, stage surviving pairs in LDS
  for (int i = s; i < V; i += STRIPES) {
    float4 pi = prc4[i];
    bool pass = false;
    if (tid > i && tid < V) {
      float4 pj = prc4[tid];
      float dx = pi.x - pj.x, dy = pi.y - pj.y;
      float rs = pi.z + pj.z;
      pass = (dx * dx + dy * dy) <= rs * rs;
    }
    u64 bal = __ballot(pass);
    if (bal) {
      int base = 0;
      if (lane == 0) base = atomicAdd(&lcnt, (int)__popcll(bal));
      base = __shfl(base, 0);
      if (pass) {
        int pos = base + (int)__popcll(bal & ((1ull << lane) - 1ull));
        if (pos < STAGE_CAP) stage[pos] = ((u32)i << 9) | (u32)tid;
      }
    }
  }
  __syncthreads();
  int tot = lcnt < STAGE_CAP ? lcnt : STAGE_CAP;
  // phase 2: clip staged pairs
  for (int p = tid; p < tot; p += 512) {
    u32 w = stage[p];
    int i = w >> 9, j = w & 511;
    const float* ca = csort + ((size_t)ci * NPROP + i) * 8;
    const float* cb = csort + ((size_t)ci * NPROP + j) * 8;
    float4 a0 = *(const float4*)ca;
    float4 a1 = *(const float4*)(ca + 4);
    float4 b0 = *(const float4*)cb;
    float4 b1 = *(const float4*)(cb + 4);
    float Ax[4] = {a0.x, a0.y, a0.z, a0.w};
    float Ay[4] = {a1.x, a1.y, a1.z, a1.w};
    float Bx[4] = {b0.x, b0.y, b0.z, b0.w};
    float By[4] = {b1.x, b1.y, b1.z, b1.w};
    float inter = inter_area_fast(Ax, Ay, Bx, By);
    float areaA = prc4[i].w;
    float areaB = prc4[j].w;
    float uni = (areaA + areaB) - inter;
    float iou = inter / fmaxf(uni, 1e-8f);
    if (iou > NMS_T)
      atomicOr(&mask[((size_t)ci * NPROP + i) * 8 + (j >> 6)], 1ull << (j & 63));
  }
}

// ---------------- kernel 3: greedy bitmask NMS scan + kept-key compaction ----------------
__global__ void k_nms(const float* __restrict__ ssort,
                      const u64* __restrict__ mask,
                      u64* __restrict__ kkey) {  // [NCI][128] sortable keys, desc, 0-filled
  int ci = blockIdx.x;
  int b = ci / FG, cfg = ci - b * FG;
  __shared__ u64 lmask[NPROP * 8];  // 32 KiB
  __shared__ u64 keptw[8];
  __shared__ int vcnt;
  __shared__ int wpre[8];
  const float* ss = ssort + ci * NPROP;
  if (threadIdx.x == 0) vcnt = NPROP;
  if (threadIdx.x < 8) keptw[threadIdx.x] = 0ull;
  __syncthreads();
  for (int i = threadIdx.x; i < NPROP; i += blockDim.x)
    if (!(ss[i] > SCORE_T)) atomicMin(&vcnt, i);
  __syncthreads();
  int V = vcnt;
  for (int x = threadIdx.x; x < V * 8; x += blockDim.x)
    lmask[x] = mask[(size_t)(ci * NPROP) * 8 + x];
  __syncthreads();
  if (threadIdx.x < 64) {
    int lane = threadIdx.x;
    u64 removed = 0ull, kb = 0ull;
    int kc = 0;
    for (int i = 0; i < V; ++i) {
      int w = i >> 6, bp = i & 63;
      u64 rw = __shfl(removed, w);
      if (!((rw >> bp) & 1ull)) {
        if (lane == w) kb |= (1ull << bp);
        if (lane < 8) removed |= lmask[i * 8 + lane];
        if (++kc >= DETS) break;  // first 100 kept fully determine output
      }
    }
    if (lane < 8) keptw[lane] = kb;
  }
  __syncthreads();
  if (threadIdx.x == 0) {
    int acc = 0;
#pragma unroll
    for (int w = 0; w < 8; ++w) { wpre[w] = acc; acc += (int)__popcll(keptw[w]); }
  }
  __syncthreads();
  for (int i = threadIdx.x; i < NPROP; i += blockDim.x) {
    u64 kw = keptw[i >> 6];
    if ((kw >> (i & 63)) & 1ull) {
      int rank = wpre[i >> 6] + (int)__popcll(kw & ((1ull << (i & 63)) - 1ull));
      float s = ss[i];
      u32 hi = __float_as_uint(s) ^ 0x80000000u;  // s > 0.05 > 0
      u32 flat = (u32)(cfg * NPROP + i);
      kkey[ci * 128 + rank] = ((u64)hi << 32) | (u32)(~flat);  // ties: lower flat wins max
    }
  }
  int total = wpre[7] + (int)__popcll(keptw[7]);
  for (int r = threadIdx.x; r < 128; r += blockDim.x)
    if (r >= total) kkey[ci * 128 + r] = 0ull;
}

// ---------------- kernel 4: 15-way merge of sorted kept lists -> top-100 ----------------
__global__ void k_topk(const u64* __restrict__ kkey,
                       const float* __restrict__ bsort,
                       float* __restrict__ out) {
  int b = blockIdx.x;  // 2 blocks, 128 threads
  __shared__ u64 lk[FG * 128];  // 15 KiB
  __shared__ u64 res[DETS];
  for (int x = threadIdx.x; x < FG * 128; x += 128) lk[x] = kkey[b * FG * 128 + x];
  for (int x = threadIdx.x; x < DETS; x += 128) res[x] = 0ull;
  __syncthreads();
  if (threadIdx.x < 64) {
    int lane = threadIdx.x;
    int pos = 0;
    u64 head = 0ull, nxt = 0ull;
    if (lane < FG) { head = lk[lane * 128]; nxt = lk[lane * 128 + 1]; }
    for (int r = 0; r < DETS; ++r) {
      u64 m = head;
#pragma unroll
      for (int wdt = 1; wdt < 64; wdt <<= 1) {
        u64 o = __shfl_xor(m, wdt);
        m = (o > m) ? o : m;
      }
      if (m == 0ull) break;  // uniform
      if (lane == 0) res[r] = m;
      if (head == m && lane < FG) {
        ++pos;
        head = nxt;
        nxt = (pos + 1 < 128) ? lk[lane * 128 + pos + 1] : 0ull;
      }
    }
  }
  __syncthreads();
  if (threadIdx.x < DETS) {
    u64 key = res[threadIdx.x];
    float* o = out + ((size_t)b * DETS + threadIdx.x) * 6;
    if (key == 0ull) {
#pragma unroll
      for (int q = 0; q < 6; ++q) o[q] = 0.f;
    } else {
      u32 flat = ~(u32)(key & 0xFFFFFFFFull);
      int cfg = flat >> 9, pos = flat & 511;
      const float* bx = bsort + (((size_t)b * FG + cfg) * NPROP + pos) * 5;
#pragma unroll
      for (int q = 0; q < 5; ++q) o[q] = bx[q];
      o[5] = __uint_as_float((u32)(key >> 32) ^ 0x80000000u);
    }
  }
}

extern "C" void kernel_launch(void* const* d_in, const int* in_sizes, int n_in,
                              void* d_out, int out_size, void* d_ws, size_t ws_size,
                              hipStream_t stream) {
  const float* logits = (const float*)d_in[0];
  const float* regr   = (const float*)d_in[1];
  const float* prop   = (const float*)d_in[2];
  float* out = (float*)d_out;

  float* ssort = (float*)d_ws;                        // 15360 f
  float* bsort = ssort + NCI * NPROP;                 // 76800 f
  float* csort = bsort + NCI * NPROP * 5;             // 122880 f
  float4* prc  = (float4*)(csort + NCI * NPROP * 8);  // 15360 float4 (16B-aligned offset)
  u64* kkey    = (u64*)(prc + NCI * NPROP);           // 3840 u64
  u64* mask    = kkey + NCI * 128;                    // 122880 u64  (total ~2.2 MB)

  hipLaunchKernelGGL(k_sortdec, dim3(NCI), dim3(256), 0, stream,
                     logits, regr, prop, ssort, bsort, csort, prc, mask);
  hipLaunchKernelGGL(k_paircl, dim3(NCI, STRIPES), dim3(512), 0, stream,
                     ssort, prc, csort, mask);
  hipLaunchKernelGGL(k_nms, dim3(NCI), dim3(256), 0, stream, ssort, mask, kkey);
  hipLaunchKernelGGL(k_topk, dim3(2), dim3(128), 0, stream, kkey, bsort, out);
}

// Round 5
// 66.093 us; speedup vs baseline: 4.0547x; 1.4618x over previous
//
#include <hip/hip_runtime.h>

#define FG 15
#define NPROP 512
#define NCLS 16
#define NCI 30   // B*FG
#define SCORE_T 0.05f
#define NMS_T 0.5f
#define DETS 100
#define STRIPES 8
#define STAGE_CAP 4096  // per-block pair staging (expected ~300/block)

typedef unsigned long long u64;
typedef unsigned int u32;

__device__ __forceinline__ unsigned sortable_f32(float f) {
  unsigned u = __float_as_uint(f);
  return u ^ ((u >> 31) ? 0xFFFFFFFFu : 0x80000000u);
}

__device__ __forceinline__ void mk_corners(const float* bx, float* X, float* Y) {
#pragma clang fp contract(off)
  float xc = bx[0], yc = bx[1], w = bx[2], h = bx[3], a = bx[4];
  float t = a * 0.017453292519943295f;
  float c = cosf(t), s = sinf(t);
  float hw = w * 0.5f, hh = h * 0.5f;
  float lx[4] = {-hw, hw, hw, -hw};
  float ly[4] = {-hh, -hh, hh, hh};
#pragma unroll
  for (int k = 0; k < 4; ++k) {
    X[k] = xc + lx[k] * c - ly[k] * s;
    Y[k] = yc + lx[k] * s + ly[k] * c;
  }
}

// ---------------- kernel 1: fused softmax+decode+sort+corners ----------------
__global__ void __launch_bounds__(256) k_sortdec(
    const float* __restrict__ logits, const float* __restrict__ regr,
    const float* __restrict__ prop,
    float* __restrict__ ssort,    // [NCI][NPROP] masked scores, sorted desc
    float* __restrict__ bsort,    // [NCI][NPROP][5]
    float* __restrict__ csort,    // [NCI][NPROP][8] x0..3,y0..3
    float4* __restrict__ prc,     // [NCI][NPROP] (x, y, circumradius, area)
    u64* __restrict__ mask) {     // zeroed here
  int ci = blockIdx.x;
  int b = ci / FG;
  int c = ci - b * FG + 1;  // class 1..15
  __shared__ float scs[NPROP];
  __shared__ float bb_s[5][NPROP];
  __shared__ u64 key[NPROP];

  for (int n = threadIdx.x; n < NPROP; n += 256) {
#pragma clang fp contract(off)
    int g = b * NPROP + n;
    const float* lg = logits + g * NCLS;
    float l[NCLS];
    float mx = -INFINITY;
#pragma unroll
    for (int q = 0; q < NCLS; ++q) { l[q] = lg[q]; mx = fmaxf(mx, l[q]); }
    float sum = 0.f, ec = 0.f;
#pragma unroll
    for (int q = 0; q < NCLS; ++q) {
      float e = expf(l[q] - mx);
      sum += e;
      if (q == c) ec = e;
    }
    float sc = ec / sum;  // bit-identical to reference path
    scs[n] = sc;
    const float* pb = prop + g * 5;
    float xc = pb[0], yc = pb[1], w = pb[2], h = pb[3], a = pb[4];
    const float* r = regr + g * 80 + c * 5;
    float dx = r[0] / 10.0f;
    float dy = r[1] / 10.0f;
    float dw = fminf(r[2] / 5.0f, 4.135166556742356f);
    float dh = fminf(r[3] / 5.0f, 4.135166556742356f);
    float da = r[4] / 10.0f;
    bb_s[0][n] = dx * w + xc;
    bb_s[1][n] = dy * h + yc;
    bb_s[2][n] = expf(dw) * w;
    bb_s[3][n] = expf(dh) * h;
    bb_s[4][n] = da * 57.29577951308232f + a;
    float m = (sc > SCORE_T) ? sc : -INFINITY;
    unsigned so = sortable_f32(m);
    key[n] = ((u64)(~so) << 32) | (unsigned)n;  // asc key = desc score, asc idx
  }
  __syncthreads();
  for (int k = 2; k <= NPROP; k <<= 1) {
    for (int j = k >> 1; j > 0; j >>= 1) {
      int t = threadIdx.x;  // 256 threads = 256 pairs
      int i1 = ((t & ~(j - 1)) << 1) | (t & (j - 1));
      int i2 = i1 | j;
      bool up = ((i1 & k) == 0);
      u64 a = key[i1], cc = key[i2];
      bool sw = up ? (a > cc) : (a < cc);
      if (sw) { key[i1] = cc; key[i2] = a; }
      __syncthreads();
    }
  }
  for (int i = threadIdx.x; i < NPROP; i += 256) {
#pragma clang fp contract(off)
    u64 kv = key[i];
    int idx = (int)(kv & 0xFFFFFFFFull);
    float v = scs[idx];
    ssort[ci * NPROP + i] = (v > SCORE_T) ? v : -INFINITY;
    float bb[5];
#pragma unroll
    for (int q = 0; q < 5; ++q) bb[q] = bb_s[q][idx];
    float* dst = bsort + (ci * NPROP + i) * 5;
#pragma unroll
    for (int q = 0; q < 5; ++q) dst[q] = bb[q];
    float X[4], Y[4];
    mk_corners(bb, X, Y);
    float* cd = csort + (ci * NPROP + i) * 8;
#pragma unroll
    for (int k = 0; k < 4; ++k) { cd[k] = X[k]; cd[4 + k] = Y[k]; }
    float rr = 0.5f * sqrtf(bb[2] * bb[2] + bb[3] * bb[3]);
    prc[ci * NPROP + i] = make_float4(bb[0], bb[1], rr, bb[2] * bb[3]);
  }
  u64* mrow = mask + (size_t)ci * NPROP * 8;
  for (int x = threadIdx.x; x < NPROP * 8; x += 256) mrow[x] = 0ull;
}

// ---------------- register Sutherland-Hodgman (fast-math; IoU slack >> rounding) --------
#define CLIP_EMIT(V, VALIDEXPR, CX, CY, NX, NY)                                \
  {                                                                            \
    bool valid = (VALIDEXPR);                                                  \
    float cx = (CX), cy = (CY), nx = (NX), ny = (NY);                          \
    float sc = ex * (cy - p1y) - ey * (cx - p1x);                              \
    float sn = ex * (ny - p1y) - ey * (nx - p1x);                              \
    bool ic = sc >= 0.f, inn = sn >= 0.f;                                      \
    float den = sc - sn;                                                       \
    float dsel = (fabsf(den) > 1e-8f) ? den : 1.f;                             \
    float tt = sc * __builtin_amdgcn_rcpf(dsel);                               \
    float qx = cx + tt * (nx - cx);                                            \
    float qy = cy + tt * (ny - cy);                                            \
    bool fC = valid && ic;                                                     \
    bool fI = valid && (ic != inn);                                            \
    _Pragma("unroll") for (int o = 0; o < 8; ++o) if (o <= 2 * (V)) {          \
      bool wr = fC && (m == o);                                                \
      ox[o] = wr ? cx : ox[o];                                                 \
      oy[o] = wr ? cy : oy[o];                                                 \
    }                                                                          \
    m += fC ? 1 : 0;                                                           \
    _Pragma("unroll") for (int o = 0; o < 8; ++o) if (o <= 2 * (V) + 1) {      \
      bool wr = fI && (m == o);                                                \
      ox[o] = wr ? qx : ox[o];                                                 \
      oy[o] = wr ? qy : oy[o];                                                 \
    }                                                                          \
    m += fI ? 1 : 0;                                                           \
  }

__device__ __forceinline__ float inter_area_fast(const float (&Ax)[4], const float (&Ay)[4],
                                                 const float (&Bx)[4], const float (&By)[4]) {
  float inx[8], iny[8];
  int n = 4;
#pragma unroll
  for (int v = 0; v < 4; ++v) {
    inx[v] = Ax[v]; iny[v] = Ay[v];
    inx[v + 4] = 0.f; iny[v + 4] = 0.f;
  }
#pragma unroll
  for (int e = 0; e < 4; ++e) {
    int e2 = (e + 1) & 3;
    float p1x = Bx[e], p1y = By[e];
    float ex = Bx[e2] - p1x, ey = By[e2] - p1y;
    float ox[8], oy[8];
    int m = 0;
#pragma unroll
    for (int o = 0; o < 8; ++o) { ox[o] = 0.f; oy[o] = 0.f; }
    if (e == 0) {  // n == 4 statically
#pragma unroll
      for (int v = 0; v < 4; ++v) {
        CLIP_EMIT(v, true, inx[v], iny[v], inx[(v + 1) & 3], iny[(v + 1) & 3]);
      }
    } else {
#pragma unroll
      for (int v = 0; v < 8; ++v) {
        bool wrap = (v + 1 >= n);
        CLIP_EMIT(v, v < n, inx[v], iny[v],
                  wrap ? inx[0] : inx[(v + 1) & 7],
                  wrap ? iny[0] : iny[(v + 1) & 7]);
      }
    }
    n = (m < 8) ? m : 8;
#pragma unroll
    for (int o = 0; o < 8; ++o) { inx[o] = ox[o]; iny[o] = oy[o]; }
  }
  float s = 0.f;
#pragma unroll
  for (int v = 0; v < 8; ++v) {
    bool valid = v < n;
    bool wrap = (v + 1 >= n);
    float axx = inx[v], ayy = iny[v];
    float bxx = wrap ? inx[0] : inx[(v + 1) & 7];
    float byy = wrap ? iny[0] : iny[(v + 1) & 7];
    float cr = axx * byy - bxx * ayy;
    s += valid ? cr : 0.f;
  }
  float area = 0.5f * fabsf(s);
  return (n >= 3) ? area : 0.f;
}

// ---------------- kernel 2: fused circle-filter + clip ----------------
// Block (ci, s) owns rows i == s (mod 8). Pair list lives only in LDS; no
// global atomics for compaction (only atomicOr on disjoint mask rows).
__global__ void __launch_bounds__(512) k_paircl(
    const float* __restrict__ ssort, const float4* __restrict__ prc,
    const float* __restrict__ csort, u64* __restrict__ mask) {
  int ci = blockIdx.x;
  int s = blockIdx.y;
  int tid = threadIdx.x;
  int lane = tid & 63;
  __shared__ float4 prc4[NPROP];   // 8 KB
  __shared__ u32 stage[STAGE_CAP]; // 16 KB
  __shared__ int vloc, lcnt;
  const float* ss = ssort + ci * NPROP;
  if (tid == 0) { vloc = NPROP; lcnt = 0; }
  __syncthreads();
  if (!(ss[tid] > SCORE_T)) atomicMin(&vloc, tid);
  prc4[tid] = prc[ci * NPROP + tid];
  __syncthreads();
  int V = vloc;
  // phase 1: circle test, stage surviving pairs in LDS
  for (int i = s; i < V; i += STRIPES) {
    float4 pi = prc4[i];
    bool pass = false;
    if (tid > i && tid < V) {
      float4 pj = prc4[tid];
      float dx = pi.x - pj.x, dy = pi.y - pj.y;
      float rs = pi.z + pj.z;
      pass = (dx * dx + dy * dy) <= rs * rs;
    }
    u64 bal = __ballot(pass);
    if (bal) {
      int base = 0;
      if (lane == 0) base = atomicAdd(&lcnt, (int)__popcll(bal));
      base = __shfl(base, 0);
      if (pass) {
        int pos = base + (int)__popcll(bal & ((1ull << lane) - 1ull));
        if (pos < STAGE_CAP) stage[pos] = ((u32)i << 9) | (u32)tid;
      }
    }
  }
  __syncthreads();
  int tot = lcnt < STAGE_CAP ? lcnt : STAGE_CAP;
  // phase 2: clip staged pairs
  for (int p = tid; p < tot; p += 512) {
    u32 w = stage[p];
    int i = w >> 9, j = w & 511;
    const float* ca = csort + ((size_t)ci * NPROP + i) * 8;
    const float* cb = csort + ((size_t)ci * NPROP + j) * 8;
    float4 a0 = *(const float4*)ca;
    float4 a1 = *(const float4*)(ca + 4);
    float4 b0 = *(const float4*)cb;
    float4 b1 = *(const float4*)(cb + 4);
    float Ax[4] = {a0.x, a0.y, a0.z, a0.w};
    float Ay[4] = {a1.x, a1.y, a1.z, a1.w};
    float Bx[4] = {b0.x, b0.y, b0.z, b0.w};
    float By[4] = {b1.x, b1.y, b1.z, b1.w};
    float inter = inter_area_fast(Ax, Ay, Bx, By);
    float areaA = prc4[i].w;
    float areaB = prc4[j].w;
    float uni = (areaA + areaB) - inter;
    float iou = inter / fmaxf(uni, 1e-8f);
    if (iou > NMS_T)
      atomicOr(&mask[((size_t)ci * NPROP + i) * 8 + (j >> 6)], 1ull << (j & 63));
  }
}

// ---------------- kernel 3: greedy bitmask NMS scan + kept-key compaction ----------------
__global__ void k_nms(const float* __restrict__ ssort,
                      const u64* __restrict__ mask,
                      u64* __restrict__ kkey) {  // [NCI][128] sortable keys, desc, 0-filled
  int ci = blockIdx.x;
  int b = ci / FG, cfg = ci - b * FG;
  __shared__ u64 lmask[NPROP * 8];  // 32 KiB
  __shared__ u64 keptw[8];
  __shared__ int vcnt;
  __shared__ int wpre[8];
  const float* ss = ssort + ci * NPROP;
  if (threadIdx.x == 0) vcnt = NPROP;
  if (threadIdx.x < 8) keptw[threadIdx.x] = 0ull;
  __syncthreads();
  for (int i = threadIdx.x; i < NPROP; i += blockDim.x)
    if (!(ss[i] > SCORE_T)) atomicMin(&vcnt, i);
  __syncthreads();
  int V = vcnt;
  for (int x = threadIdx.x; x < V * 8; x += blockDim.x)
    lmask[x] = mask[(size_t)(ci * NPROP) * 8 + x];
  __syncthreads();
  if (threadIdx.x < 64) {
    int lane = threadIdx.x;
    u64 removed = 0ull, kb = 0ull;
    int kc = 0;
    for (int i = 0; i < V; ++i) {
      int w = i >> 6, bp = i & 63;
      u64 rw = __shfl(removed, w);
      if (!((rw >> bp) & 1ull)) {
        if (lane == w) kb |= (1ull << bp);
        if (lane < 8) removed |= lmask[i * 8 + lane];
        if (++kc >= DETS) break;  // first 100 kept fully determine output
      }
    }
    if (lane < 8) keptw[lane] = kb;
  }
  __syncthreads();
  if (threadIdx.x == 0) {
    int acc = 0;
#pragma unroll
    for (int w = 0; w < 8; ++w) { wpre[w] = acc; acc += (int)__popcll(keptw[w]); }
  }
  __syncthreads();
  for (int i = threadIdx.x; i < NPROP; i += blockDim.x) {
    u64 kw = keptw[i >> 6];
    if ((kw >> (i & 63)) & 1ull) {
      int rank = wpre[i >> 6] + (int)__popcll(kw & ((1ull << (i & 63)) - 1ull));
      float s = ss[i];
      u32 hi = __float_as_uint(s) ^ 0x80000000u;  // s > 0.05 > 0
      u32 flat = (u32)(cfg * NPROP + i);
      kkey[ci * 128 + rank] = ((u64)hi << 32) | (u32)(~flat);  // ties: lower flat wins max
    }
  }
  int total = wpre[7] + (int)__popcll(keptw[7]);
  for (int r = threadIdx.x; r < 128; r += blockDim.x)
    if (r >= total) kkey[ci * 128 + r] = 0ull;
}

// ---------------- kernel 4: parallel rank-select top-100 ----------------
// All real keys are strictly distinct (flat idx embedded), so output slot of a
// key == its exact rank = #keys greater, summed over the 15 desc-sorted lists
// via branchless binary search. Unique ranks => collision-free scatter.
__global__ void __launch_bounds__(1024) k_topk(
    const u64* __restrict__ kkey,
    const float* __restrict__ bsort,
    float* __restrict__ out) {
  int b = blockIdx.x;  // 2 blocks, 1024 threads
  __shared__ u64 lk[FG * 128];  // 15 KiB
  __shared__ u64 res[DETS];
  for (int x = threadIdx.x; x < FG * 128; x += 1024) lk[x] = kkey[b * FG * 128 + x];
  for (int x = threadIdx.x; x < DETS; x += 1024) res[x] = 0ull;
  __syncthreads();
  for (int x = threadIdx.x; x < FG * 128; x += 1024) {
    u64 key = lk[x];
    if (key == 0ull) continue;  // real keys have hi bit set (score > 0)
    int rank = 0;
#pragma unroll
    for (int c = 0; c < FG; ++c) {
      const u64* a = &lk[c * 128];
      int pos = 0;
#pragma unroll
      for (int st = 64; st > 0; st >>= 1)
        pos += (a[pos + st - 1] > key) ? st : 0;  // pos in [0,127]
      rank += pos + ((a[pos] > key) ? 1 : 0);
    }
    if (rank < DETS) res[rank] = key;
  }
  __syncthreads();
  if (threadIdx.x < DETS) {
    u64 key = res[threadIdx.x];
    float* o = out + ((size_t)b * DETS + threadIdx.x) * 6;
    if (key == 0ull) {
#pragma unroll
      for (int q = 0; q < 6; ++q) o[q] = 0.f;
    } else {
      u32 flat = ~(u32)(key & 0xFFFFFFFFull);
      int cfg = flat >> 9, pos = flat & 511;
      const float* bx = bsort + (((size_t)b * FG + cfg) * NPROP + pos) * 5;
#pragma unroll
      for (int q = 0; q < 5; ++q) o[q] = bx[q];
      o[5] = __uint_as_float((u32)(key >> 32) ^ 0x80000000u);
    }
  }
}

extern "C" void kernel_launch(void* const* d_in, const int* in_sizes, int n_in,
                              void* d_out, int out_size, void* d_ws, size_t ws_size,
                              hipStream_t stream) {
  const float* logits = (const float*)d_in[0];
  const float* regr   = (const float*)d_in[1];
  const float* prop   = (const float*)d_in[2];
  float* out = (float*)d_out;

  float* ssort = (float*)d_ws;                        // 15360 f
  float* bsort = ssort + NCI * NPROP;                 // 76800 f
  float* csort = bsort + NCI * NPROP * 5;             // 122880 f
  float4* prc  = (float4*)(csort + NCI * NPROP * 8);  // 15360 float4 (16B-aligned offset)
  u64* kkey    = (u64*)(prc + NCI * NPROP);           // 3840 u64
  u64* mask    = kkey + NCI * 128;                    // 122880 u64  (total ~2.2 MB)

  hipLaunchKernelGGL(k_sortdec, dim3(NCI), dim3(256), 0, stream,
                     logits, regr, prop, ssort, bsort, csort, prc, mask);
  hipLaunchKernelGGL(k_paircl, dim3(NCI, STRIPES), dim3(512), 0, stream,
                     ssort, prc, csort, mask);
  hipLaunchKernelGGL(k_nms, dim3(NCI), dim3(256), 0, stream, ssort, mask, kkey);
  hipLaunchKernelGGL(k_topk, dim3(2), dim3(1024), 0, stream, kkey, bsort, out);
}